// Round 1
// 100.532 us; speedup vs baseline: 1.0155x; 1.0155x over previous
//
#include <hip/hip_runtime.h>
#include <math.h>

#define NPTS 8192
#define NCHUNK 32  // 32 target chunks of 256 points

struct Xforms { float B[3][4]; float R[3][4]; float T[3][4]; };

__device__ __forceinline__ void compute_xforms(const float* __restrict__ quat,
                                               const float* __restrict__ bt,
                                               const float* __restrict__ anchor,
                                               const float* __restrict__ axis,
                                               const float* __restrict__ theta,
                                               Xforms& X) {
  float q0 = quat[0], q1 = quat[1], q2 = quat[2], q3 = quat[3];
  float n = sqrtf(q0 * q0 + q1 * q1 + q2 * q2 + q3 * q3);
  float a = q0 / n, b = q1 / n, c = q2 / n, d = q3 / n;
  X.B[0][0] = 1.f - 2.f * c * c - 2.f * d * d;
  X.B[0][1] = 2.f * b * c - 2.f * a * d;
  X.B[0][2] = 2.f * a * c + 2.f * b * d;
  X.B[0][3] = bt[0];
  X.B[1][0] = 2.f * b * c + 2.f * a * d;
  X.B[1][1] = 1.f - 2.f * b * b - 2.f * d * d;
  X.B[1][2] = 2.f * c * d - 2.f * a * b;
  X.B[1][3] = bt[1];
  X.B[2][0] = 2.f * b * d - 2.f * a * c;
  X.B[2][1] = 2.f * a * b + 2.f * c * d;
  X.B[2][2] = 1.f - 2.f * b * b - 2.f * c * c;
  X.B[2][3] = bt[2];

  float ax = anchor[0], ay = anchor[1], az = anchor[2];
  float u = axis[0], v = axis[1], w = axis[2];
  float th = theta[0];
  float cs = cosf(th), sn = sinf(th), oc = 1.f - cs;
  X.R[0][0] = u * u + (v * v + w * w) * cs;
  X.R[0][1] = u * v * oc - w * sn;
  X.R[0][2] = u * w * oc + v * sn;
  X.R[0][3] = (ax * (v * v + w * w) - u * (ay * v + az * w)) * oc + (ay * w - az * v) * sn;
  X.R[1][0] = u * v * oc + w * sn;
  X.R[1][1] = v * v + (u * u + w * w) * cs;
  X.R[1][2] = v * w * oc - u * sn;
  X.R[1][3] = (ay * (u * u + w * w) - v * (ax * u + az * w)) * oc + (az * u - ax * w) * sn;
  X.R[2][0] = u * w * oc - v * sn;
  X.R[2][1] = v * w * oc + u * sn;
  X.R[2][2] = w * w + (u * u + v * v) * cs;
  X.R[2][3] = (az * (u * u + v * v) - w * (ax * u + ay * v)) * oc + (ax * v - ay * u) * sn;

#pragma unroll
  for (int i = 0; i < 3; i++) {
#pragma unroll
    for (int j = 0; j < 4; j++) {
      float s = X.R[i][0] * X.B[0][j] + X.R[i][1] * X.B[1][j] + X.R[i][2] * X.B[2][j];
      if (j == 3) s += X.R[i][3];
      X.T[i][j] = s;
    }
  }
}

// Fused transform + chamfer partial-min. grid (4 src-chunks, 32 tgt-chunks,
// 4 combos), block 256. combo c: src array = c, tgt array = c^1, where
// a=0: B*cad0, a=1: cam0, a=2: T*cad1, a=3: cam1. Exactly one side of each
// combo is a transformed cad cloud; the other gets an exact identity matrix
// (1.0f*x + 0.0f*y adds are bitwise-exact), so results match the staged
// version bit-for-bit. No atomics: each block writes its 256-pt-chunk min
// to partial[combo][tgt_chunk][src_pt] with plain coalesced stores.
__global__ __launch_bounds__(256) void chamfer_kernel(
    const float* __restrict__ cam, const float* __restrict__ cad,
    const float* __restrict__ quat, const float* __restrict__ bt,
    const float* __restrict__ anchor, const float* __restrict__ axis,
    const float* __restrict__ theta,
    float* __restrict__ partial, float* __restrict__ sums,
    unsigned int* __restrict__ counter) {
  const int combo = blockIdx.z;
  const int tid = threadIdx.x;

  // One block initializes the reducer's accumulators (kernel boundary
  // guarantees visibility to the next launch; no other block touches these).
  if (blockIdx.x == 0 && blockIdx.y == 0 && combo == 0) {
    if (tid < 4) sums[tid] = 0.f;
    if (tid == 4) *counter = 0u;
  }

  Xforms X;
  compute_xforms(quat, bt, anchor, axis, theta, X);

  const int part = combo >> 1;
  const int src_is_cad = ((combo & 1) == 0) ? 1 : 0;

  // Per-element selects keep matrices in registers (no dynamic indexing).
  float Ms[3][4], Mt[3][4];
#pragma unroll
  for (int r = 0; r < 3; r++) {
#pragma unroll
    for (int c = 0; c < 4; c++) {
      float m = part ? X.T[r][c] : X.B[r][c];
      float id = (r == c) ? 1.f : 0.f;
      Ms[r][c] = src_is_cad ? m : id;
      Mt[r][c] = src_is_cad ? id : m;
    }
  }

  const float* __restrict__ srcbase = (src_is_cad ? cad : cam) + part * NPTS * 3;
  const float* __restrict__ tgtbase = (src_is_cad ? cam : cad) + part * NPTS * 3;

  const int sbase = blockIdx.x * 2048;
  float4 s[8];
  float vmin[8];
#pragma unroll
  for (int i = 0; i < 8; i++) {
    int idx = (sbase + i * 256 + tid) * 3;
    float px = srcbase[idx + 0], py = srcbase[idx + 1], pz = srcbase[idx + 2];
    float qx = Ms[0][0] * px + Ms[0][1] * py + Ms[0][2] * pz + Ms[0][3];
    float qy = Ms[1][0] * px + Ms[1][1] * py + Ms[1][2] * pz + Ms[1][3];
    float qz = Ms[2][0] * px + Ms[2][1] * py + Ms[2][2] * pz + Ms[2][3];
    s[i] = make_float4(qx, qy, qz, 0.5f * (qx * qx + qy * qy + qz * qz));
    vmin[i] = 3.4e38f;
  }

  __shared__ float4 tile[256];
  {
    int idx = (blockIdx.y * 256 + tid) * 3;
    float px = tgtbase[idx + 0], py = tgtbase[idx + 1], pz = tgtbase[idx + 2];
    float qx = Mt[0][0] * px + Mt[0][1] * py + Mt[0][2] * pz + Mt[0][3];
    float qy = Mt[1][0] * px + Mt[1][1] * py + Mt[1][2] * pz + Mt[1][3];
    float qz = Mt[2][0] * px + Mt[2][1] * py + Mt[2][2] * pz + Mt[2][3];
    tile[tid] = make_float4(qx, qy, qz, 0.5f * (qx * qx + qy * qy + qz * qz));
  }
  __syncthreads();

  // min d^2 = 2*(s.w + min_k(t.w - s·t)); 2 targets per iter so the two new
  // candidates + running min fold into v_min3_f32.
#pragma unroll 2
  for (int k = 0; k < 256; k += 2) {
    float4 t0 = tile[k];
    float4 t1 = tile[k + 1];
#pragma unroll
    for (int i = 0; i < 8; i++) {
      float v0 = fmaf(-s[i].z, t0.z, t0.w);
      v0 = fmaf(-s[i].y, t0.y, v0);
      v0 = fmaf(-s[i].x, t0.x, v0);
      float v1 = fmaf(-s[i].z, t1.z, t1.w);
      v1 = fmaf(-s[i].y, t1.y, v1);
      v1 = fmaf(-s[i].x, t1.x, v1);
      vmin[i] = fminf(vmin[i], fminf(v0, v1));
    }
  }

  float* __restrict__ pp = partial + (combo * NCHUNK + blockIdx.y) * NPTS + sbase;
#pragma unroll
  for (int i = 0; i < 8; i++) {
    pp[i * 256 + tid] = fmaxf(0.f, 2.f * (s[i].w + vmin[i]));
  }
}

// 32 blocks: 8 per combo, 1024 src pts each. Register fmin over the 32
// tgt-chunk partials (exact: float min is order-independent), then sqrt-sum
// with the same per-thread grouping as the previously-passing version.
// atomicAdd partial sums + last-block-done finalize (device scope, XCD-safe).
__global__ __launch_bounds__(256) void reduce_finalize_kernel(
    const float* __restrict__ partial, float* __restrict__ sums,
    unsigned int* __restrict__ counter,
    const float* __restrict__ pw,
    const float* __restrict__ quat, const float* __restrict__ bt,
    const float* __restrict__ anchor, const float* __restrict__ axis,
    const float* __restrict__ theta, float* __restrict__ out) {
  const int tid = threadIdx.x;
  const int combo = blockIdx.x >> 3;
  const int chunk = blockIdx.x & 7;
  const int sofs = chunk * 1024;

  float m0 = 3.4e38f, m1 = 3.4e38f, m2 = 3.4e38f, m3 = 3.4e38f;
#pragma unroll 8
  for (int t = 0; t < NCHUNK; t++) {
    const float* __restrict__ p = partial + (combo * NCHUNK + t) * NPTS + sofs;
    m0 = fminf(m0, p[0 * 256 + tid]);
    m1 = fminf(m1, p[1 * 256 + tid]);
    m2 = fminf(m2, p[2 * 256 + tid]);
    m3 = fminf(m3, p[3 * 256 + tid]);
  }
  float ssum = sqrtf(m0) + sqrtf(m1) + sqrtf(m2) + sqrtf(m3);

#pragma unroll
  for (int off = 32; off > 0; off >>= 1) ssum += __shfl_down(ssum, off);
  __shared__ float part[4];
  if ((tid & 63) == 0) part[tid >> 6] = ssum;
  __syncthreads();

  if (tid == 0) {
    float blocksum = part[0] + part[1] + part[2] + part[3];
    atomicAdd(&sums[combo], blocksum);
    __threadfence();
    unsigned int old = atomicAdd(counter, 1u);
    if (old == 31u) {  // all other blocks' sums are visible
      __threadfence();
      float s0 = __hip_atomic_load(&sums[0], __ATOMIC_ACQUIRE, __HIP_MEMORY_SCOPE_AGENT);
      float s1 = __hip_atomic_load(&sums[1], __ATOMIC_ACQUIRE, __HIP_MEMORY_SCOPE_AGENT);
      float s2 = __hip_atomic_load(&sums[2], __ATOMIC_ACQUIRE, __HIP_MEMORY_SCOPE_AGENT);
      float s3 = __hip_atomic_load(&sums[3], __ATOMIC_ACQUIRE, __HIP_MEMORY_SCOPE_AGENT);
      Xforms X;
      compute_xforms(quat, bt, anchor, axis, theta, X);
      const float inv = 1.0f / (float)NPTS;
      float base_obj = (s0 + s1) * inv;
      float child_obj = (s2 + s3) * inv;
      out[0] = (pw[0] * base_obj + pw[1] * child_obj) * 0.5f;
      out[1] = base_obj;
      out[2] = child_obj;
      for (int i = 0; i < 3; i++)
        for (int j = 0; j < 4; j++) out[3 + i * 4 + j] = X.B[i][j];
      out[15] = 0.f; out[16] = 0.f; out[17] = 0.f; out[18] = 1.f;
      for (int i = 0; i < 3; i++)
        for (int j = 0; j < 4; j++) out[19 + i * 4 + j] = X.R[i][j];
      out[31] = 0.f; out[32] = 0.f; out[33] = 0.f; out[34] = 1.f;
    }
  }
}

extern "C" void kernel_launch(void* const* d_in, const int* in_sizes, int n_in,
                              void* d_out, int out_size, void* d_ws, size_t ws_size,
                              hipStream_t stream) {
  const float* cam  = (const float*)d_in[0];  // [2,8192,3]
  const float* cad  = (const float*)d_in[1];  // [2,8192,3]
  const float* xyz  = (const float*)d_in[2];  // [1,3] anchor
  const float* rpy  = (const float*)d_in[3];  // [1,3] axis
  const float* pw   = (const float*)d_in[4];  // [2]
  const float* quat = (const float*)d_in[5];  // [4]
  const float* bt   = (const float*)d_in[6];  // [3,1]
  const float* js   = (const float*)d_in[7];  // [1]

  // ws layout: partial 4 MB (4 combos x 32 chunks x 8192 f32) | sums 16 B | counter 4 B
  float* partial = (float*)d_ws;
  float* sums = (float*)((char*)d_ws + 4 * NCHUNK * NPTS * sizeof(float));
  unsigned int* counter = (unsigned int*)(sums + 4);
  float* out = (float*)d_out;

  hipLaunchKernelGGL(chamfer_kernel, dim3(4, NCHUNK, 4), dim3(256), 0, stream,
                     cam, cad, quat, bt, xyz, rpy, js, partial, sums, counter);
  hipLaunchKernelGGL(reduce_finalize_kernel, dim3(32), dim3(256), 0, stream,
                     partial, sums, counter, pw, quat, bt, xyz, rpy, js, out);
}